// Round 6
// baseline (128.258 us; speedup 1.0000x reference)
//
#include <hip/hip_runtime.h>

// Exact (non-approximate) GELU, matching jax.nn.gelu(approximate=False).
__device__ __forceinline__ float gelu_exact(float x) {
    return 0.5f * x * (1.0f + erff(x * 0.7071067811865475f));
}

__device__ __forceinline__ float dot4(float4 a, float4 b) {
    return a.x * b.x + a.y * b.y + a.z * b.z + a.w * b.w;
}

// Kernel A: evaluate the 5-layer MLP at the constant input [0,0,1,1].
// One block, 1024 threads, 4 threads per output neuron (split-K over 64).
// All three 256x256 weight matrices are prefetched into registers UP FRONT
// (48 float4 = 192 VGPRs) so the HBM loads for layers 2,3,4 are all in
// flight simultaneously instead of serialized by the layer syncs.
__global__ __launch_bounds__(1024) void mlp_weights_kernel(
    const float* __restrict__ W1, const float* __restrict__ b1,
    const float* __restrict__ W2, const float* __restrict__ b2,
    const float* __restrict__ W3, const float* __restrict__ b3,
    const float* __restrict__ W4, const float* __restrict__ b4,
    const float* __restrict__ W5, const float* __restrict__ b5,
    float* __restrict__ wout)
{
    __shared__ __align__(16) float xs[256];
    const int t = threadIdx.x;
    const int j = t >> 2;   // output neuron 0..255
    const int s = t & 3;    // k-slice 0..3 (64 elements each)

    // Layer-1 inputs first — they gate the whole chain.
    // inp = [0,0,1,1]; W1 is [256,4] row-major: pre[j] = W1[j,2]+W1[j,3]+b1[j]
    float l1pre = 0.f;
    if (t < 256) {
        float4 w1r = *reinterpret_cast<const float4*>(W1 + t * 4);
        l1pre = w1r.z + w1r.w + b1[t];
    }

    // Prefetch: issue ALL big-layer weight loads now (global, in-order issue).
    float4 w2r[16], w3r[16], w4r[16];
    const float4* p2 = reinterpret_cast<const float4*>(W2 + j * 256 + s * 64);
    const float4* p3 = reinterpret_cast<const float4*>(W3 + j * 256 + s * 64);
    const float4* p4 = reinterpret_cast<const float4*>(W4 + j * 256 + s * 64);
    #pragma unroll
    for (int k = 0; k < 16; ++k) w2r[k] = p2[k];
    #pragma unroll
    for (int k = 0; k < 16; ++k) w3r[k] = p3[k];
    #pragma unroll
    for (int k = 0; k < 16; ++k) w4r[k] = p4[k];
    const float bj2 = b2[j];
    const float bj3 = b3[j];
    const float bj4 = b4[j];

    // Layer 1 -> xs
    if (t < 256) xs[t] = gelu_exact(l1pre);
    __syncthreads();

    const float4* xv = reinterpret_cast<const float4*>(xs) + s * 16;

    // Layer 2 (from registers)
    {
        float acc = 0.f;
        #pragma unroll
        for (int k = 0; k < 16; ++k) acc += dot4(w2r[k], xv[k]);
        acc += __shfl_xor(acc, 1);
        acc += __shfl_xor(acc, 2);
        float g = gelu_exact(acc + bj2);
        __syncthreads();
        if (s == 0) xs[j] = g;
        __syncthreads();
    }
    // Layer 3
    {
        float acc = 0.f;
        #pragma unroll
        for (int k = 0; k < 16; ++k) acc += dot4(w3r[k], xv[k]);
        acc += __shfl_xor(acc, 1);
        acc += __shfl_xor(acc, 2);
        float g = gelu_exact(acc + bj3);
        __syncthreads();
        if (s == 0) xs[j] = g;
        __syncthreads();
    }
    // Layer 4
    {
        float acc = 0.f;
        #pragma unroll
        for (int k = 0; k < 16; ++k) acc += dot4(w4r[k], xv[k]);
        acc += __shfl_xor(acc, 1);
        acc += __shfl_xor(acc, 2);
        float g = gelu_exact(acc + bj4);
        __syncthreads();
        if (s == 0) xs[j] = g;
        __syncthreads();
    }

    // Layer 5: W5 is [12,256]; 12 outputs, 4 threads each (small, loaded late).
    if (t < 48) {
        const float4* p5 = reinterpret_cast<const float4*>(W5 + j * 256 + s * 64);
        float acc = 0.f;
        #pragma unroll
        for (int k = 0; k < 16; ++k) acc += dot4(p5[k], xv[k]);
        acc += __shfl_xor(acc, 1);
        acc += __shfl_xor(acc, 2);
        if (s == 0) wout[j] = acc + b5[j];
    }
}

// Kernel B: pred[b,p,d] = sum_c feat[b,c,p] * w[c*3+d].
// feat: [B=4, C=4, HW=65536] fp32, out: [B, HW, 3] fp32.
// Each thread handles 4 consecutive pixels: 4x float4 loads (one per
// channel plane), 48 FMAs, 3x float4 stores (48B contiguous, 16B aligned).
__global__ __launch_bounds__(256) void apply_kernel(
    const float* __restrict__ feat, const float* __restrict__ w12,
    float* __restrict__ out)
{
    const int idx = blockIdx.x * 256 + threadIdx.x;  // 0..65535
    const int b   = idx >> 14;                        // 16384 chunks per batch
    const int pos = (idx & 16383) << 2;               // pixel start (multiple of 4)

    const float* fb = feat + (size_t)b * 4 * 65536 + pos;
    const float4 f0 = *reinterpret_cast<const float4*>(fb);
    const float4 f1 = *reinterpret_cast<const float4*>(fb + 65536);
    const float4 f2 = *reinterpret_cast<const float4*>(fb + 131072);
    const float4 f3 = *reinterpret_cast<const float4*>(fb + 196608);

    float w[12];
    #pragma unroll
    for (int i = 0; i < 12; ++i) w[i] = w12[i];

    float r[12];
    #pragma unroll
    for (int dd = 0; dd < 3; ++dd) {
        r[0 + dd] = f0.x * w[dd] + f1.x * w[3 + dd] + f2.x * w[6 + dd] + f3.x * w[9 + dd];
        r[3 + dd] = f0.y * w[dd] + f1.y * w[3 + dd] + f2.y * w[6 + dd] + f3.y * w[9 + dd];
        r[6 + dd] = f0.z * w[dd] + f1.z * w[3 + dd] + f2.z * w[6 + dd] + f3.z * w[9 + dd];
        r[9 + dd] = f0.w * w[dd] + f1.w * w[3 + dd] + f2.w * w[6 + dd] + f3.w * w[9 + dd];
    }

    float* op = out + (size_t)(b * 65536 + pos) * 3;
    reinterpret_cast<float4*>(op)[0] = make_float4(r[0], r[1], r[2],  r[3]);
    reinterpret_cast<float4*>(op)[1] = make_float4(r[4], r[5], r[6],  r[7]);
    reinterpret_cast<float4*>(op)[2] = make_float4(r[8], r[9], r[10], r[11]);
}

extern "C" void kernel_launch(void* const* d_in, const int* in_sizes, int n_in,
                              void* d_out, int out_size, void* d_ws, size_t ws_size,
                              hipStream_t stream) {
    const float* feat = (const float*)d_in[0];
    const float* W1   = (const float*)d_in[1];
    const float* b1   = (const float*)d_in[2];
    const float* W2   = (const float*)d_in[3];
    const float* b2   = (const float*)d_in[4];
    const float* W3   = (const float*)d_in[5];
    const float* b3   = (const float*)d_in[6];
    const float* W4   = (const float*)d_in[7];
    const float* b4   = (const float*)d_in[8];
    const float* W5   = (const float*)d_in[9];
    const float* b5   = (const float*)d_in[10];

    float* wout = (float*)d_ws;          // 12 floats of scratch
    float* out  = (float*)d_out;         // [4, 65536, 3] fp32

    mlp_weights_kernel<<<1, 1024, 0, stream>>>(W1, b1, W2, b2, W3, b3,
                                               W4, b4, W5, b5, wout);
    // B*HW/4 threads = 65536 -> 256 blocks x 256 threads
    apply_kernel<<<256, 256, 0, stream>>>(feat, wout, out);
}

// Round 7
// 84.782 us; speedup vs baseline: 1.5128x; 1.5128x over previous
//
#include <hip/hip_runtime.h>

// Exact (non-approximate) GELU, matching jax.nn.gelu(approximate=False).
__device__ __forceinline__ float gelu_exact(float x) {
    return 0.5f * x * (1.0f + erff(x * 0.7071067811865475f));
}

__device__ __forceinline__ float dot4(float4 a, float4 b) {
    return a.x * b.x + a.y * b.y + a.z * b.z + a.w * b.w;
}

// Full 64-lane wave reduce (sum).
__device__ __forceinline__ float wave_reduce(float acc) {
    #pragma unroll
    for (int off = 32; off >= 1; off >>= 1) acc += __shfl_xor(acc, off);
    return acc;
}

// L1+L2 fused: every block recomputes x1 (4KB of W1, L2-cached), then its
// 4 waves each compute one x2 neuron. grid = 64 blocks x 256 threads.
__global__ __launch_bounds__(256) void layer12_kernel(
    const float* __restrict__ W1, const float* __restrict__ b1,
    const float* __restrict__ W2, const float* __restrict__ b2,
    float* __restrict__ xout)
{
    __shared__ __align__(16) float xs[256];
    const int t = threadIdx.x;

    // x1[t] = gelu(W1[t,2] + W1[t,3] + b1[t])   (MLP input is [0,0,1,1])
    float4 w1r = *reinterpret_cast<const float4*>(W1 + t * 4);
    xs[t] = gelu_exact(w1r.z + w1r.w + b1[t]);
    __syncthreads();

    const int w = t >> 6;                    // wave 0..3
    const int l = t & 63;                    // lane
    const int j = blockIdx.x * 4 + w;        // output neuron 0..255

    float4 wv = *reinterpret_cast<const float4*>(W2 + j * 256 + l * 4);
    float4 x4 = *reinterpret_cast<const float4*>(xs + l * 4);
    float acc = wave_reduce(dot4(wv, x4));
    if (l == 0) xout[j] = gelu_exact(acc + b2[j]);
}

// Generic 256->256 layer: one wave per output neuron.
// grid = 64 blocks x 256 threads.
__global__ __launch_bounds__(256) void layer_kernel(
    const float* __restrict__ W, const float* __restrict__ b,
    const float* __restrict__ xin, float* __restrict__ xout)
{
    const int t = threadIdx.x;
    const int w = t >> 6;
    const int l = t & 63;
    const int j = blockIdx.x * 4 + w;

    float4 wv = *reinterpret_cast<const float4*>(W + j * 256 + l * 4);
    float4 x4 = *reinterpret_cast<const float4*>(xin + l * 4);
    float acc = wave_reduce(dot4(wv, x4));
    if (l == 0) xout[j] = gelu_exact(acc + b[j]);
}

// Layer 5: W5 [12,256], no activation. 1 block x 768 threads (12 waves).
__global__ __launch_bounds__(768) void layer5_kernel(
    const float* __restrict__ W5, const float* __restrict__ b5,
    const float* __restrict__ xin, float* __restrict__ wout)
{
    const int t = threadIdx.x;
    const int j = t >> 6;                    // wave = output 0..11
    const int l = t & 63;

    float4 wv = *reinterpret_cast<const float4*>(W5 + j * 256 + l * 4);
    float4 x4 = *reinterpret_cast<const float4*>(xin + l * 4);
    float acc = wave_reduce(dot4(wv, x4));
    if (l == 0) wout[j] = acc + b5[j];
}

// Kernel B: pred[b,p,d] = sum_c feat[b,c,p] * w[c*3+d].
// feat: [B=4, C=4, HW=65536] fp32, out: [B, HW, 3] fp32.
// Each thread handles 4 consecutive pixels: 4x float4 loads (one per
// channel plane), 48 FMAs, 3x float4 stores (48B contiguous, 16B aligned).
__global__ __launch_bounds__(256) void apply_kernel(
    const float* __restrict__ feat, const float* __restrict__ w12,
    float* __restrict__ out)
{
    const int idx = blockIdx.x * 256 + threadIdx.x;  // 0..65535
    const int b   = idx >> 14;                        // 16384 chunks per batch
    const int pos = (idx & 16383) << 2;               // pixel start (multiple of 4)

    const float* fb = feat + (size_t)b * 4 * 65536 + pos;
    const float4 f0 = *reinterpret_cast<const float4*>(fb);
    const float4 f1 = *reinterpret_cast<const float4*>(fb + 65536);
    const float4 f2 = *reinterpret_cast<const float4*>(fb + 131072);
    const float4 f3 = *reinterpret_cast<const float4*>(fb + 196608);

    float w[12];
    #pragma unroll
    for (int i = 0; i < 12; ++i) w[i] = w12[i];

    float r[12];
    #pragma unroll
    for (int dd = 0; dd < 3; ++dd) {
        r[0 + dd] = f0.x * w[dd] + f1.x * w[3 + dd] + f2.x * w[6 + dd] + f3.x * w[9 + dd];
        r[3 + dd] = f0.y * w[dd] + f1.y * w[3 + dd] + f2.y * w[6 + dd] + f3.y * w[9 + dd];
        r[6 + dd] = f0.z * w[dd] + f1.z * w[3 + dd] + f2.z * w[6 + dd] + f3.z * w[9 + dd];
        r[9 + dd] = f0.w * w[dd] + f1.w * w[3 + dd] + f2.w * w[6 + dd] + f3.w * w[9 + dd];
    }

    float* op = out + (size_t)(b * 65536 + pos) * 3;
    reinterpret_cast<float4*>(op)[0] = make_float4(r[0], r[1], r[2],  r[3]);
    reinterpret_cast<float4*>(op)[1] = make_float4(r[4], r[5], r[6],  r[7]);
    reinterpret_cast<float4*>(op)[2] = make_float4(r[8], r[9], r[10], r[11]);
}

extern "C" void kernel_launch(void* const* d_in, const int* in_sizes, int n_in,
                              void* d_out, int out_size, void* d_ws, size_t ws_size,
                              hipStream_t stream) {
    const float* feat = (const float*)d_in[0];
    const float* W1   = (const float*)d_in[1];
    const float* b1   = (const float*)d_in[2];
    const float* W2   = (const float*)d_in[3];
    const float* b2   = (const float*)d_in[4];
    const float* W3   = (const float*)d_in[5];
    const float* b3   = (const float*)d_in[6];
    const float* W4   = (const float*)d_in[7];
    const float* b4   = (const float*)d_in[8];
    const float* W5   = (const float*)d_in[9];
    const float* b5   = (const float*)d_in[10];

    float* wsf  = (float*)d_ws;
    float* wout = wsf;              // 12 floats
    float* xA   = wsf + 16;         // 256 floats, 64B-aligned
    float* xB   = wsf + 16 + 256;   // 256 floats

    float* out = (float*)d_out;     // [4, 65536, 3] fp32

    layer12_kernel<<<64, 256, 0, stream>>>(W1, b1, W2, b2, xA);        // x2 -> A
    layer_kernel  <<<64, 256, 0, stream>>>(W3, b3, xA, xB);            // x3 -> B
    layer_kernel  <<<64, 256, 0, stream>>>(W4, b4, xB, xA);            // x4 -> A
    layer5_kernel <<<1, 768, 0, stream>>>(W5, b5, xA, wout);           // 12 weights
    apply_kernel  <<<256, 256, 0, stream>>>(feat, wout, out);
}